// Round 1
// baseline (1374.184 us; speedup 1.0000x reference)
//
#include <hip/hip_runtime.h>

// NodePropagatorSparse: out[b,e,0:256] = ns[b,src[e],:]; out[b,e,256:512] = ns[b,tgt[e],:]
// B=4, N=10000, E=160000, D=256. Pure gather/concat -> HBM write-bound (~1.31 GB out).

constexpr int B = 4;
constexpr int N = 10000;
constexpr int E = 160000;
constexpr int D = 256;          // floats per half-row
constexpr int D4 = D / 4;       // 64 float4 per half-row (one wave at 16 B/lane)

using f32x4 = __attribute__((ext_vector_type(4))) float;

__global__ __launch_bounds__(256) void NodePropagatorSparse_kernel(
    const f32x4* __restrict__ ns,    // [B, N, D4] float4
    const int*   __restrict__ src,   // [E]
    const int*   __restrict__ tgt,   // [E]
    f32x4*       __restrict__ out)   // [B, E, 2*D4] float4
{
    // Each 256-thread block handles 2 (b,e) slots:
    //   threads   0..63  -> src half of slot 0 (wave 0, uniform index)
    //   threads  64..127 -> tgt half of slot 0 (wave 1)
    //   threads 128..191 -> src half of slot 1 (wave 2)
    //   threads 192..255 -> tgt half of slot 1 (wave 3)
    const int slot = blockIdx.x * 2 + (threadIdx.x >> 7);   // in [0, B*E)
    const int b    = slot / E;
    const int e    = slot - b * E;
    const int t    = threadIdx.x & 127;   // position within the 128-float4 out row
    const int half = t >> 6;              // 0 = src, 1 = tgt (wave-uniform)
    const int col  = t & 63;              // float4 column within the 256-float row

    const int node = half ? tgt[e] : src[e];   // wave-uniform -> scalar load

    const f32x4 v = ns[(b * N + node) * D4 + col];

    // Streamed output, never re-read: nontemporal store keeps L2/L3 for ns.
    __builtin_nontemporal_store(v, &out[slot * (2 * D4) + t]);
}

extern "C" void kernel_launch(void* const* d_in, const int* in_sizes, int n_in,
                              void* d_out, int out_size, void* d_ws, size_t ws_size,
                              hipStream_t stream) {
    const f32x4* ns  = (const f32x4*)d_in[0];
    const int*   src = (const int*)d_in[1];
    const int*   tgt = (const int*)d_in[2];
    f32x4*       out = (f32x4*)d_out;

    const int blocks = (B * E) / 2;   // 320,000 blocks x 256 threads, 1 float4/thread
    NodePropagatorSparse_kernel<<<blocks, 256, 0, stream>>>(ns, src, tgt, out);
}